// Round 4
// baseline (1523.406 us; speedup 1.0000x reference)
//
#include <hip/hip_runtime.h>
#include <hip/hip_bf16.h>

#define BB 256      // batch
#define TT 2048     // timesteps
#define DD 32       // obs dim
#define HH 64       // hidden
#define GG 256      // 4*H gates
#define CHUNK 64    // timesteps of x per LDS refill
#define NCH (TT / CHUNK)

__device__ __forceinline__ float fast_sig(float x) {
    return __builtin_amdgcn_rcpf(1.0f + __expf(-x));
}

// Barrier that drains ONLY LDS ops (lgkmcnt), leaving global loads/stores
// in flight. __syncthreads() would emit s_waitcnt vmcnt(0) expcnt(0)
// lgkmcnt(0) -- forcing a full HBM store-retire wait every step.
__device__ __forceinline__ void lds_barrier() {
    asm volatile("s_waitcnt lgkmcnt(0)" ::: "memory");
    __builtin_amdgcn_s_barrier();
    asm volatile("" ::: "memory");
}

__global__ __launch_bounds__(256, 1) void lstm_seq_kernel(
    const float* __restrict__ y,    // [B, T, D]
    const float* __restrict__ Wx,   // [D, 4H]
    const float* __restrict__ Wh,   // [H, 4H]
    const float* __restrict__ b,    // [4H]
    float* __restrict__ out)        // [B, T, H]
{
    const int j = threadIdx.x;        // gate column 0..255
    const int w = j >> 6;             // wave id
    const int l = j & 63;             // lane / hidden unit
    const int batch = blockIdx.x;

    __shared__ float xbuf[4][CHUNK * DD];  // per-wave PRIVATE x chunk (8 KB each)
    __shared__ float hbuf[4][HH];          // per-wave PRIVATE h copy
    __shared__ float gbuf[2][GG];          // double-buffered activated gates

    // weight columns in registers (coalesced: fixed k, consecutive j)
    float wx[DD];
#pragma unroll
    for (int k = 0; k < DD; ++k) wx[k] = Wx[k * GG + j];
    float wh[HH];
#pragma unroll
    for (int k = 0; k < HH; ++k) wh[k] = Wh[k * GG + j];
    const float bj = b[j];

    // wave-uniform activation: sigmoid for i,f,o; tanh(x)=2*sig(2x)-1 for g (wave 2)
    const bool isg = (w == 2);
    const float sc = isg ? 2.0f : 1.0f;
    const float aa = isg ? 2.0f : 1.0f;
    const float ab = isg ? -1.0f : 0.0f;

    float c = 0.0f;                   // replicated cell state for unit l
    hbuf[w][l] = 0.0f;                // own-wave copy (in-wave ordering suffices)

    const float4* ysrc = (const float4*)(y + (size_t)batch * (TT * DD)); // 512 float4 per chunk
    float* obase = out + (size_t)batch * (TT * HH);

    // prefetch chunk 0 into registers: 2048 floats/wave, 8 float4 per lane
    float4 pf[8];
#pragma unroll
    for (int q = 0; q < 8; ++q) pf[q] = ysrc[q * 64 + l];

    __syncthreads();   // once, at init -- cost irrelevant

    int buf = 0;
    for (int ch = 0; ch < NCH; ++ch) {
        // ---- commit prefetched chunk to OWN wave's xbuf (in-wave LDS ordering;
        //      only this wave reads xbuf[w], so no barrier needed)
        float4* xw = (float4*)xbuf[w];
#pragma unroll
        for (int q = 0; q < 8; ++q) xw[q * 64 + l] = pf[q];
        // ---- prefetch NEXT chunk (consumed ~64 steps from now; stays in
        //      flight across lds_barrier -- no vmcnt drain anymore)
        {
            const int cn = (ch + 1 < NCH) ? (ch + 1) : ch;
#pragma unroll
            for (int q = 0; q < 8; ++q) pf[q] = ysrc[cn * 512 + q * 64 + l];
        }

        for (int tl = 0; tl < CHUNK; ++tl) {
            const int t = ch * CHUNK + tl;
            // ---- h reads issue first; latency hides under x-FMA block
            const float4* hp = (const float4*)hbuf[w];
            const float4* xp = (const float4*)(xbuf[w] + tl * DD);

            float a0 = bj, a1 = 0.0f, a2 = 0.0f, a3 = 0.0f;
#pragma unroll
            for (int q = 0; q < DD / 4; ++q) {
                float4 xv = xp[q];
                a0 = fmaf(xv.x, wx[4 * q + 0], a0);
                a1 = fmaf(xv.y, wx[4 * q + 1], a1);
                a2 = fmaf(xv.z, wx[4 * q + 2], a2);
                a3 = fmaf(xv.w, wx[4 * q + 3], a3);
            }
#pragma unroll
            for (int k = 0; k < HH / 4; ++k) {
                float4 hv = hp[k];
                a0 = fmaf(hv.x, wh[4 * k + 0], a0);
                a1 = fmaf(hv.y, wh[4 * k + 1], a1);
                a2 = fmaf(hv.z, wh[4 * k + 2], a2);
                a3 = fmaf(hv.w, wh[4 * k + 3], a3);
            }
            float g = (a0 + a1) + (a2 + a3);
            // activation by the gate owner (parallel across all 256 threads)
            gbuf[buf][j] = fmaf(aa, fast_sig(sc * g), ab);
            lds_barrier();   // the ONLY barrier per step; vmcnt stays in flight

            // ---- every wave redundantly updates its replica of (c, h)
            float ig = gbuf[buf][l];
            float fg = gbuf[buf][HH + l];
            float gg = gbuf[buf][2 * HH + l];
            float og = gbuf[buf][3 * HH + l];
            c = fmaf(fg, c, ig * gg);
            float th = fmaf(2.0f, fast_sig(2.0f * c), -1.0f);   // tanh(c)
            float h = og * th;
            hbuf[w][l] = h;                         // own copy; in-wave ordering
            if (w == 0) obase[(size_t)t * HH + l] = h;  // store stays in flight
            buf ^= 1;
        }
    }
}

extern "C" void kernel_launch(void* const* d_in, const int* in_sizes, int n_in,
                              void* d_out, int out_size, void* d_ws, size_t ws_size,
                              hipStream_t stream) {
    const float* y  = (const float*)d_in[0];
    const float* Wx = (const float*)d_in[1];
    const float* Wh = (const float*)d_in[2];
    const float* b  = (const float*)d_in[3];
    float* out = (float*)d_out;

    lstm_seq_kernel<<<BB, GG, 0, stream>>>(y, Wx, Wh, b, out);
}

// Round 5
// 1354.973 us; speedup vs baseline: 1.1243x; 1.1243x over previous
//
#include <hip/hip_runtime.h>
#include <hip/hip_bf16.h>

#define BB 256      // batch
#define TT 2048     // timesteps
#define DD 32       // obs dim
#define HH 64       // hidden
#define GG 256      // 4*H gates

__device__ __forceinline__ float fast_sig(float x) {
    return __builtin_amdgcn_rcpf(1.0f + __expf(-x));
}
__device__ __forceinline__ float rdlane(float v, int k) {
    return __uint_as_float(__builtin_amdgcn_readlane(__float_as_uint(v), k));
}
// LDS-only barrier: drain lgkmcnt, leave global loads/stores in flight.
__device__ __forceinline__ void lds_barrier() {
    asm volatile("s_waitcnt lgkmcnt(0)" ::: "memory");
    __builtin_amdgcn_s_barrier();
    asm volatile("" ::: "memory");
}

__global__ __launch_bounds__(256, 1) void lstm_seq_kernel(
    const float* __restrict__ y,    // [B, T, D]
    const float* __restrict__ Wx,   // [D, 4H]
    const float* __restrict__ Wh,   // [H, 4H]
    const float* __restrict__ b,    // [4H]
    float* __restrict__ out)        // [B, T, H]
{
    const int j = threadIdx.x;        // gate column 0..255
    const int w = j >> 6;             // wave id = gate type (0=i,1=f,2=g,3=o)
    const int l = j & 63;             // lane = hidden unit
    const int batch = blockIdx.x;

    __shared__ float gbuf[2][4][HH];  // [buf][gate][unit]; the ONLY LDS traffic

    // weight columns in registers (coalesced: fixed k, consecutive j)
    float wx[DD];
#pragma unroll
    for (int k = 0; k < DD; ++k) wx[k] = Wx[k * GG + j];
    float wh[HH];
#pragma unroll
    for (int k = 0; k < HH; ++k) wh[k] = Wh[k * GG + j];
    const float bj = b[j];

    // wave-uniform activation: sigmoid for i,f,o; tanh(x)=2*sig(2x)-1 for g
    const bool isg = (w == 2);
    const float sc = isg ? 2.0f : 1.0f;
    const float aa = isg ? 2.0f : 1.0f;
    const float ab = isg ? -1.0f : 0.0f;

    float c = 0.0f;     // lane l's replica of c[l] (identical in all 4 waves)
    float h = 0.0f;     // lane l's replica of h[l]

    const float* ybase = y + (size_t)batch * (TT * DD);
    float* obase = out + (size_t)batch * (TT * HH);

    // x row broadcast-loaded into registers, double-buffered (xa / xb).
    float4 xa[DD / 4], xb[DD / 4];
    {
        const float4* r0 = (const float4*)ybase;
#pragma unroll
        for (int q = 0; q < DD / 4; ++q) xa[q] = r0[q];
    }

    // One LSTM step. XC: current x row (regs); XN: prefetch target for row t+1.
    // Static BUFI / array indices everywhere (no scratch spill).
#define STEP(XC, XN, BUFI, TI)                                                 \
    {                                                                          \
        /* prefetch next x row; stays in flight through the whole step */     \
        const int tn_ = ((TI) + 1 < TT) ? ((TI) + 1) : (TI);                   \
        const float4* nrow_ = (const float4*)(ybase + (size_t)tn_ * DD);       \
        _Pragma("unroll")                                                      \
        for (int q = 0; q < DD / 4; ++q) XN[q] = nrow_[q];                     \
        /* gates: 4-way ILP accumulators, x part from regs */                  \
        float ac0 = bj, ac1 = 0.0f, ac2 = 0.0f, ac3 = 0.0f;                    \
        _Pragma("unroll")                                                      \
        for (int q = 0; q < DD / 4; ++q) {                                     \
            ac0 = fmaf(XC[q].x, wx[4 * q + 0], ac0);                           \
            ac1 = fmaf(XC[q].y, wx[4 * q + 1], ac1);                           \
            ac2 = fmaf(XC[q].z, wx[4 * q + 2], ac2);                           \
            ac3 = fmaf(XC[q].w, wx[4 * q + 3], ac3);                           \
        }                                                                      \
        /* h part: readlane broadcast, zero LDS */                             \
        _Pragma("unroll")                                                      \
        for (int k4 = 0; k4 < HH / 4; ++k4) {                                  \
            ac0 = fmaf(rdlane(h, 4 * k4 + 0), wh[4 * k4 + 0], ac0);            \
            ac1 = fmaf(rdlane(h, 4 * k4 + 1), wh[4 * k4 + 1], ac1);            \
            ac2 = fmaf(rdlane(h, 4 * k4 + 2), wh[4 * k4 + 2], ac2);            \
            ac3 = fmaf(rdlane(h, 4 * k4 + 3), wh[4 * k4 + 3], ac3);            \
        }                                                                      \
        float g_ = (ac0 + ac1) + (ac2 + ac3);                                  \
        gbuf[BUFI][w][l] = fmaf(aa, fast_sig(sc * g_), ab);                    \
        lds_barrier();                                                         \
        float ig_ = gbuf[BUFI][0][l];                                          \
        float fg_ = gbuf[BUFI][1][l];                                          \
        float gg_ = gbuf[BUFI][2][l];                                          \
        float og_ = gbuf[BUFI][3][l];                                          \
        c = fmaf(fg_, c, ig_ * gg_);                                           \
        float th_ = fmaf(2.0f, fast_sig(2.0f * c), -1.0f); /* tanh(c) */       \
        h = og_ * th_;                                                         \
        if (w == 0) obase[(size_t)(TI) * HH + l] = h;                          \
    }

    for (int t = 0; t < TT; t += 2) {
        STEP(xa, xb, 0, t);       // consume xa, prefetch into xb
        STEP(xb, xa, 1, t + 1);   // consume xb, prefetch into xa
    }
#undef STEP
}

extern "C" void kernel_launch(void* const* d_in, const int* in_sizes, int n_in,
                              void* d_out, int out_size, void* d_ws, size_t ws_size,
                              hipStream_t stream) {
    const float* y  = (const float*)d_in[0];
    const float* Wx = (const float*)d_in[1];
    const float* Wh = (const float*)d_in[2];
    const float* b  = (const float*)d_in[3];
    float* out = (float*)d_out;

    lstm_seq_kernel<<<BB, GG, 0, stream>>>(y, Wx, Wh, b, out);
}